// Round 2
// baseline (1198.476 us; speedup 1.0000x reference)
//
#include <hip/hip_runtime.h>

// Pipeline: morph open/close -> conv1+bn1 -> conv2+pool+bn2 -> conv3+bn3
//           -> conv4+globalmax -> dense -> h_maxima (50 dilate+min steps)
// All fp32. Workspace usage ~107 MB (see layout in kernel_launch).

#define B_ 32
#define H_ 256
#define W_ 256

__device__ __forceinline__ float4 ld4(const float* p){ return *reinterpret_cast<const float4*>(p); }
__device__ __forceinline__ void st4(float* p, float4 v){ *reinterpret_cast<float4*>(p) = v; }

// ---------------- morphology: 3x3 dilation (max, +k) / erosion (min, -k_flipped) ----------------
// out[y,x] = max_{di,dj} in[y+di,x+dj] + k[di+1][dj+1]          (dilation)
// out[y,x] = min_{di,dj} in[y+di,x+dj] - k[1-di][1-dj]          (erosion)
// borders: pad with -inf (dilation) / +inf (erosion) == skip OOB taps.
template<int IS_MAX>
__global__ void morph_k(const float* __restrict__ in, float* __restrict__ out,
                        const float* __restrict__ k9)
{
    int t = blockIdx.x * blockDim.x + threadIdx.x;     // quad index
    int xq = t & 63; int y = (t >> 6) & 255; int b = t >> 14;
    if (b >= B_) return;
    const float INF = __builtin_inff();
    const float* img = in + (size_t)b * (H_ * W_);
    int x0 = xq * 4;
    float res[4];
    #pragma unroll
    for (int j = 0; j < 4; ++j) res[j] = IS_MAX ? -INF : INF;
    #pragma unroll
    for (int di = -1; di <= 1; ++di) {
        int yy = y + di;
        if (yy < 0 || yy >= H_) continue;
        const float* row = img + yy * W_;
        float w[6];
        w[0] = (x0 > 0) ? row[x0 - 1] : (IS_MAX ? -INF : INF);
        float4 m = ld4(row + x0);
        w[1] = m.x; w[2] = m.y; w[3] = m.z; w[4] = m.w;
        w[5] = (x0 + 4 < W_) ? row[x0 + 4] : (IS_MAX ? -INF : INF);
        #pragma unroll
        for (int dj = -1; dj <= 1; ++dj) {
            float kv = IS_MAX ? k9[(di + 1) * 3 + (dj + 1)]
                              : k9[(1 - di) * 3 + (1 - dj)];
            #pragma unroll
            for (int j = 0; j < 4; ++j) {
                float v = IS_MAX ? (w[j + 1 + dj] + kv) : (w[j + 1 + dj] - kv);
                res[j] = IS_MAX ? fmaxf(res[j], v) : fminf(res[j], v);
            }
        }
    }
    st4(out + (size_t)b * (H_ * W_) + y * W_ + x0,
        make_float4(res[0], res[1], res[2], res[3]));
}

// ---------------- conv1 (3x3,1->8) + relu + bn1 ----------------
__global__ void conv1_k(const float* __restrict__ xc, float* __restrict__ y1,
                        const float* __restrict__ w, const float* __restrict__ bias,
                        const float* __restrict__ g, const float* __restrict__ bb,
                        const float* __restrict__ mn, const float* __restrict__ vr)
{
    const int S = 254;
    int t = blockIdx.x * blockDim.x + threadIdx.x;
    int total = B_ * S * S;
    if (t >= total) return;
    int x = t % S; int y = (t / S) % S; int b = t / (S * S);
    const float* img = xc + (size_t)b * H_ * W_;
    float acc[8];
    #pragma unroll
    for (int c = 0; c < 8; ++c) acc[c] = bias[c];
    #pragma unroll
    for (int ky = 0; ky < 3; ++ky) {
        #pragma unroll
        for (int kx = 0; kx < 3; ++kx) {
            float iv = img[(y + ky) * W_ + (x + kx)];
            const float* wp = w + (ky * 3 + kx) * 8;
            #pragma unroll
            for (int c = 0; c < 8; ++c) acc[c] = fmaf(iv, wp[c], acc[c]);
        }
    }
    float* op = y1 + (size_t)t * 8;
    #pragma unroll
    for (int c = 0; c < 8; ++c) {
        float z = fmaxf(acc[c], 0.f);
        float s = g[c] / sqrtf(vr[c] + 1.0e-3f);
        op[c] = fmaf(s, z, bb[c] - mn[c] * s);
    }
}

// ---------------- conv2 (3x3,8->16) + relu + maxpool2 + bn2 ----------------
__global__ void conv2_k(const float* __restrict__ y1, float* __restrict__ y2,
                        const float* __restrict__ w, const float* __restrict__ bias,
                        const float* __restrict__ g, const float* __restrict__ bb,
                        const float* __restrict__ mn, const float* __restrict__ vr)
{
    const int P = 126, SIN = 254;
    int t = blockIdx.x * blockDim.x + threadIdx.x;
    int total = B_ * P * P;
    if (t >= total) return;
    int px = t % P; int py = (t / P) % P; int b = t / (P * P);
    const float* imgb = y1 + (size_t)b * SIN * SIN * 8;
    float best[16];
    #pragma unroll
    for (int c = 0; c < 16; ++c) best[c] = 0.f;   // relu outputs >= 0
    #pragma unroll 1
    for (int pos = 0; pos < 4; ++pos) {
        int oy = 2 * py + (pos >> 1), ox = 2 * px + (pos & 1);
        float acc[16];
        #pragma unroll
        for (int c = 0; c < 16; ++c) acc[c] = bias[c];
        #pragma unroll 1
        for (int tap = 0; tap < 9; ++tap) {
            int ky = tap / 3, kx = tap - ky * 3;
            const float* ip = imgb + ((size_t)(oy + ky) * SIN + (ox + kx)) * 8;
            float4 a = ld4(ip), c4 = ld4(ip + 4);
            float in8[8] = {a.x, a.y, a.z, a.w, c4.x, c4.y, c4.z, c4.w};
            const float* wp = w + tap * 8 * 16;
            #pragma unroll
            for (int ci = 0; ci < 8; ++ci)
                #pragma unroll
                for (int co = 0; co < 16; ++co)
                    acc[co] = fmaf(in8[ci], wp[ci * 16 + co], acc[co]);
        }
        #pragma unroll
        for (int co = 0; co < 16; ++co)
            best[co] = fmaxf(best[co], fmaxf(acc[co], 0.f));
    }
    float* op = y2 + (size_t)t * 16;
    #pragma unroll
    for (int c = 0; c < 16; ++c) {
        float s = g[c] / sqrtf(vr[c] + 1.0e-3f);
        op[c] = fmaf(s, best[c], bb[c] - mn[c] * s);
    }
}

// ---------------- conv3 (3x3,16->32) + relu + bn3 ----------------
__global__ void conv3_k(const float* __restrict__ y2, float* __restrict__ y3,
                        const float* __restrict__ w, const float* __restrict__ bias,
                        const float* __restrict__ g, const float* __restrict__ bb,
                        const float* __restrict__ mn, const float* __restrict__ vr)
{
    const int S = 124, SIN = 126;
    int t = blockIdx.x * blockDim.x + threadIdx.x;
    int total = B_ * S * S;
    if (t >= total) return;
    int x = t % S; int y = (t / S) % S; int b = t / (S * S);
    const float* imgb = y2 + (size_t)b * SIN * SIN * 16;
    float acc[32];
    #pragma unroll
    for (int c = 0; c < 32; ++c) acc[c] = bias[c];
    #pragma unroll 1
    for (int tap = 0; tap < 9; ++tap) {
        int ky = tap / 3, kx = tap - ky * 3;
        const float* ip = imgb + ((size_t)(y + ky) * SIN + (x + kx)) * 16;
        float in_r[16];
        #pragma unroll
        for (int k2 = 0; k2 < 4; ++k2) {
            float4 q = ld4(ip + k2 * 4);
            in_r[k2 * 4 + 0] = q.x; in_r[k2 * 4 + 1] = q.y;
            in_r[k2 * 4 + 2] = q.z; in_r[k2 * 4 + 3] = q.w;
        }
        const float* wp = w + tap * 16 * 32;
        #pragma unroll
        for (int ci = 0; ci < 16; ++ci)
            #pragma unroll
            for (int co = 0; co < 32; ++co)
                acc[co] = fmaf(in_r[ci], wp[ci * 32 + co], acc[co]);
    }
    float* op = y3 + (size_t)t * 32;
    #pragma unroll
    for (int c = 0; c < 32; ++c) {
        float z = fmaxf(acc[c], 0.f);
        float s = g[c] / sqrtf(vr[c] + 1.0e-3f);
        op[c] = fmaf(s, z, bb[c] - mn[c] * s);
    }
}

// ---------------- conv4 (3x3,32->32) + relu + global max per (b,c) ----------------
// maxpool2 followed by global HxW max == global max over the full 122x122 map.
__global__ void conv4max_k(const float* __restrict__ y3, float* __restrict__ maxbuf,
                           const float* __restrict__ w, const float* __restrict__ bias)
{
    const int S = 122, SIN = 124, NPIX = S * S;   // 14884
    const int NB = 59;                            // ceil(14884/256)
    int b = blockIdx.x / NB;
    int pix = (blockIdx.x % NB) * 256 + threadIdx.x;
    float r[32];
    if (pix < NPIX) {
        int x = pix % S, y = pix / S;
        const float* imgb = y3 + (size_t)b * SIN * SIN * 32;
        float acc[32];
        #pragma unroll
        for (int c = 0; c < 32; ++c) acc[c] = bias[c];
        #pragma unroll 1
        for (int tap = 0; tap < 9; ++tap) {
            int ky = tap / 3, kx = tap - ky * 3;
            const float* ip = imgb + ((size_t)(y + ky) * SIN + (x + kx)) * 32;
            float in_r[32];
            #pragma unroll
            for (int k2 = 0; k2 < 8; ++k2) {
                float4 q = ld4(ip + k2 * 4);
                in_r[k2 * 4 + 0] = q.x; in_r[k2 * 4 + 1] = q.y;
                in_r[k2 * 4 + 2] = q.z; in_r[k2 * 4 + 3] = q.w;
            }
            const float* wp = w + tap * 32 * 32;
            #pragma unroll
            for (int ci = 0; ci < 32; ++ci)
                #pragma unroll
                for (int co = 0; co < 32; ++co)
                    acc[co] = fmaf(in_r[ci], wp[ci * 32 + co], acc[co]);
        }
        #pragma unroll
        for (int c = 0; c < 32; ++c) r[c] = fmaxf(acc[c], 0.f);
    } else {
        #pragma unroll
        for (int c = 0; c < 32; ++c) r[c] = 0.f;   // identity for max of relu
    }
    // block reduction: wave shuffle then LDS across 4 waves
    int lane = threadIdx.x & 63, wid = threadIdx.x >> 6;
    __shared__ float red[4 * 32];
    #pragma unroll 1
    for (int c = 0; c < 32; ++c) {
        float v = r[c];
        #pragma unroll
        for (int off = 32; off >= 1; off >>= 1)
            v = fmaxf(v, __shfl_xor(v, off, 64));
        if (lane == 0) red[wid * 32 + c] = v;
    }
    __syncthreads();
    if (threadIdx.x < 32) {
        int c = threadIdx.x;
        float mx = fmaxf(fmaxf(red[0 * 32 + c], red[1 * 32 + c]),
                         fmaxf(red[2 * 32 + c], red[3 * 32 + c]));
        // post-relu values are >= 0, so int compare == float compare; maxbuf zero-init'd
        atomicMax(reinterpret_cast<int*>(maxbuf) + b * 32 + c, __float_as_int(mx));
    }
}

// ---------------- dense: h[b] = dot(max[b,:], dense_w) + dense_b ----------------
__global__ void dense_k(const float* __restrict__ maxbuf, const float* __restrict__ dw,
                        const float* __restrict__ db, float* __restrict__ hbuf,
                        float* __restrict__ out_h)
{
    int t = threadIdx.x;
    if (t < B_) {
        float acc = db[0];
        #pragma unroll
        for (int c = 0; c < 32; ++c) acc = fmaf(maxbuf[t * 32 + c], dw[c], acc);
        hbuf[t] = acc;
        out_h[t] = acc;
    }
}

// ---------------- h_maxima marker init: m0 = xc - h[b] ----------------
__global__ void minit_k(const float* __restrict__ xc, const float* __restrict__ hbuf,
                        float* __restrict__ m0)
{
    int t = blockIdx.x * blockDim.x + threadIdx.x;
    int b = t >> 14;
    if (b >= B_) return;
    float hv = hbuf[b];
    float4 a = ld4(xc + (size_t)t * 4);
    st4(m0 + (size_t)t * 4, make_float4(a.x - hv, a.y - hv, a.z - hv, a.w - hv));
}

// ---------------- h_maxima step: out = min(dilate3x3(m), mask) ----------------
__global__ void step_k(const float* __restrict__ m, const float* __restrict__ mask,
                       float* __restrict__ out)
{
    int t = blockIdx.x * blockDim.x + threadIdx.x;
    int xq = t & 63; int y = (t >> 6) & 255; int b = t >> 14;
    if (b >= B_) return;
    const float INF = __builtin_inff();
    const float* img = m + (size_t)b * (H_ * W_);
    int x0 = xq * 4;
    float r0 = -INF, r1 = -INF, r2 = -INF, r3 = -INF;
    #pragma unroll
    for (int di = -1; di <= 1; ++di) {
        int yy = y + di;
        if (yy < 0 || yy >= H_) continue;
        const float* row = img + yy * W_;
        float w0 = (x0 > 0) ? row[x0 - 1] : -INF;
        float4 mm = ld4(row + x0);
        float w5 = (x0 + 4 < W_) ? row[x0 + 4] : -INF;
        r0 = fmaxf(r0, fmaxf(fmaxf(w0, mm.x), mm.y));
        r1 = fmaxf(r1, fmaxf(fmaxf(mm.x, mm.y), mm.z));
        r2 = fmaxf(r2, fmaxf(fmaxf(mm.y, mm.z), mm.w));
        r3 = fmaxf(r3, fmaxf(fmaxf(mm.z, mm.w), w5));
    }
    float4 mk = ld4(mask + (size_t)t * 4);
    st4(out + (size_t)t * 4,
        make_float4(fminf(r0, mk.x), fminf(r1, mk.y), fminf(r2, mk.z), fminf(r3, mk.w)));
}

extern "C" void kernel_launch(void* const* d_in, const int* in_sizes, int n_in,
                              void* d_out, int out_size, void* d_ws, size_t ws_size,
                              hipStream_t stream) {
    const float* x    = (const float*)d_in[0];
    const float* ko   = (const float*)d_in[1];
    const float* kc   = (const float*)d_in[2];
    const float* c1w  = (const float*)d_in[3];
    const float* c1b  = (const float*)d_in[4];
    const float* c2w  = (const float*)d_in[5];
    const float* c2b  = (const float*)d_in[6];
    const float* c3w  = (const float*)d_in[7];
    const float* c3b  = (const float*)d_in[8];
    const float* c4w  = (const float*)d_in[9];
    const float* c4b  = (const float*)d_in[10];
    const float* bn1g = (const float*)d_in[11];
    const float* bn1b = (const float*)d_in[12];
    const float* bn1m = (const float*)d_in[13];
    const float* bn1v = (const float*)d_in[14];
    const float* bn2g = (const float*)d_in[15];
    const float* bn2b = (const float*)d_in[16];
    const float* bn2m = (const float*)d_in[17];
    const float* bn2v = (const float*)d_in[18];
    const float* bn3g = (const float*)d_in[19];
    const float* bn3b = (const float*)d_in[20];
    const float* bn3m = (const float*)d_in[21];
    const float* bn3v = (const float*)d_in[22];
    const float* dw   = (const float*)d_in[23];
    const float* db   = (const float*)d_in[24];
    float* out = (float*)d_out;
    float* ws  = (float*)d_ws;

    // workspace layout (floats):
    //   xc:  [0, 2097152)                      mask, persists
    //   A:   [2097152, 18613248)               morph t0/t1, then y1 (B*254*254*8),
    //                                          then y3 (B*124*124*32), then marker ping/pong
    //   B:   [18613248, 26741760)              y2 (B*126*126*16)
    //   maxbuf: [26741760, 26742784)           32*32 per-(b,c) maxima
    //   hbuf:   [26742784, 26742816)
    // total ~107 MB
    float* xc     = ws;
    float* A      = ws + 2097152;
    float* Bbuf   = ws + 18613248;
    float* maxbuf = ws + 26741760;
    float* hbuf   = ws + 26742784;
    float* t0 = A;
    float* t1 = A + 2097152;

    const int NQ_BLOCKS = (B_ * H_ * W_ / 4) / 256;  // 2048

    // morphological open then close: xc = erode(dilate(dilate(erode(x,ko),ko),kc),kc)
    morph_k<0><<<NQ_BLOCKS, 256, 0, stream>>>(x,  t0, ko);   // erosion
    morph_k<1><<<NQ_BLOCKS, 256, 0, stream>>>(t0, t1, ko);   // dilation -> xo
    morph_k<1><<<NQ_BLOCKS, 256, 0, stream>>>(t1, t0, kc);   // dilation
    morph_k<0><<<NQ_BLOCKS, 256, 0, stream>>>(t0, xc, kc);   // erosion  -> xc

    conv1_k<<<(B_ * 254 * 254 + 255) / 256, 256, 0, stream>>>(xc, A, c1w, c1b,
                                                              bn1g, bn1b, bn1m, bn1v);
    conv2_k<<<(B_ * 126 * 126 + 255) / 256, 256, 0, stream>>>(A, Bbuf, c2w, c2b,
                                                              bn2g, bn2b, bn2m, bn2v);
    conv3_k<<<(B_ * 124 * 124 + 255) / 256, 256, 0, stream>>>(Bbuf, A, c3w, c3b,
                                                              bn3g, bn3b, bn3m, bn3v);
    hipMemsetAsync(maxbuf, 0, 32 * 32 * sizeof(float), stream);
    conv4max_k<<<B_ * 59, 256, 0, stream>>>(A, maxbuf, c4w, c4b);
    dense_k<<<1, 64, 0, stream>>>(maxbuf, dw, db, hbuf, out + B_ * H_ * W_);

    // h-maxima: marker = xc - h; 50x m = min(dilate3(m), xc); last step writes d_out
    minit_k<<<NQ_BLOCKS, 256, 0, stream>>>(xc, hbuf, t0);
    for (int i = 0; i < 50; ++i) {
        const float* src = (i & 1) ? t1 : t0;
        float* dst = (i == 49) ? out : ((i & 1) ? t0 : t1);
        step_k<<<NQ_BLOCKS, 256, 0, stream>>>(src, xc, dst);
    }
}

// Round 5
// 674.023 us; speedup vs baseline: 1.7781x; 1.7781x over previous
//
#include <hip/hip_runtime.h>

// Pipeline: morph open/close -> conv1+bn1 -> conv2+pool+bn2 -> conv3+bn3
//           -> conv4+globalmax -> dense -> h_maxima (10x 5-step fused dilate+min)
// All fp32. conv3/conv4 are LDS-tiled; h-maxima runs 5 reconstruction steps
// per launch in LDS (64x32 core, halo (8,5), clamped-window updates, OOB=-inf).

#define B_ 32
#define H_ 256
#define W_ 256

__device__ __forceinline__ float4 ld4(const float* p){ return *reinterpret_cast<const float4*>(p); }
__device__ __forceinline__ void st4(float* p, float4 v){ *reinterpret_cast<float4*>(p) = v; }
__device__ __forceinline__ void st4s(float* p, float4 v){ *reinterpret_cast<float4*>(p) = v; }

// ---------------- morphology: 3x3 dilation (max, +k) / erosion (min, -k_flipped) ----------------
template<int IS_MAX>
__global__ void morph_k(const float* __restrict__ in, float* __restrict__ out,
                        const float* __restrict__ k9)
{
    int t = blockIdx.x * blockDim.x + threadIdx.x;     // quad index
    int xq = t & 63; int y = (t >> 6) & 255; int b = t >> 14;
    if (b >= B_) return;
    const float INF = __builtin_inff();
    const float* img = in + (size_t)b * (H_ * W_);
    int x0 = xq * 4;
    float res[4];
    #pragma unroll
    for (int j = 0; j < 4; ++j) res[j] = IS_MAX ? -INF : INF;
    #pragma unroll
    for (int di = -1; di <= 1; ++di) {
        int yy = y + di;
        if (yy < 0 || yy >= H_) continue;
        const float* row = img + yy * W_;
        float w[6];
        w[0] = (x0 > 0) ? row[x0 - 1] : (IS_MAX ? -INF : INF);
        float4 m = ld4(row + x0);
        w[1] = m.x; w[2] = m.y; w[3] = m.z; w[4] = m.w;
        w[5] = (x0 + 4 < W_) ? row[x0 + 4] : (IS_MAX ? -INF : INF);
        #pragma unroll
        for (int dj = -1; dj <= 1; ++dj) {
            float kv = IS_MAX ? k9[(di + 1) * 3 + (dj + 1)]
                              : k9[(1 - di) * 3 + (1 - dj)];
            #pragma unroll
            for (int j = 0; j < 4; ++j) {
                float v = IS_MAX ? (w[j + 1 + dj] + kv) : (w[j + 1 + dj] - kv);
                res[j] = IS_MAX ? fmaxf(res[j], v) : fminf(res[j], v);
            }
        }
    }
    st4(out + (size_t)b * (H_ * W_) + y * W_ + x0,
        make_float4(res[0], res[1], res[2], res[3]));
}

// ---------------- conv1 (3x3,1->8) + relu + bn1 ----------------
__global__ void conv1_k(const float* __restrict__ xc, float* __restrict__ y1,
                        const float* __restrict__ w, const float* __restrict__ bias,
                        const float* __restrict__ g, const float* __restrict__ bb,
                        const float* __restrict__ mn, const float* __restrict__ vr)
{
    const int S = 254;
    int t = blockIdx.x * blockDim.x + threadIdx.x;
    int total = B_ * S * S;
    if (t >= total) return;
    int x = t % S; int y = (t / S) % S; int b = t / (S * S);
    const float* img = xc + (size_t)b * H_ * W_;
    float acc[8];
    #pragma unroll
    for (int c = 0; c < 8; ++c) acc[c] = bias[c];
    #pragma unroll
    for (int ky = 0; ky < 3; ++ky) {
        #pragma unroll
        for (int kx = 0; kx < 3; ++kx) {
            float iv = img[(y + ky) * W_ + (x + kx)];
            const float* wp = w + (ky * 3 + kx) * 8;
            #pragma unroll
            for (int c = 0; c < 8; ++c) acc[c] = fmaf(iv, wp[c], acc[c]);
        }
    }
    float* op = y1 + (size_t)t * 8;
    #pragma unroll
    for (int c = 0; c < 8; ++c) {
        float z = fmaxf(acc[c], 0.f);
        float s = g[c] / sqrtf(vr[c] + 1.0e-3f);
        op[c] = fmaf(s, z, bb[c] - mn[c] * s);
    }
}

// ---------------- conv2 (3x3,8->16) + relu + maxpool2 + bn2 ----------------
__global__ void conv2_k(const float* __restrict__ y1, float* __restrict__ y2,
                        const float* __restrict__ w, const float* __restrict__ bias,
                        const float* __restrict__ g, const float* __restrict__ bb,
                        const float* __restrict__ mn, const float* __restrict__ vr)
{
    const int P = 126, SIN = 254;
    int t = blockIdx.x * blockDim.x + threadIdx.x;
    int total = B_ * P * P;
    if (t >= total) return;
    int px = t % P; int py = (t / P) % P; int b = t / (P * P);
    const float* imgb = y1 + (size_t)b * SIN * SIN * 8;
    float best[16];
    #pragma unroll
    for (int c = 0; c < 16; ++c) best[c] = 0.f;   // relu outputs >= 0
    #pragma unroll 1
    for (int pos = 0; pos < 4; ++pos) {
        int oy = 2 * py + (pos >> 1), ox = 2 * px + (pos & 1);
        float acc[16];
        #pragma unroll
        for (int c = 0; c < 16; ++c) acc[c] = bias[c];
        #pragma unroll 1
        for (int tap = 0; tap < 9; ++tap) {
            int ky = tap / 3, kx = tap - ky * 3;
            const float* ip = imgb + ((size_t)(oy + ky) * SIN + (ox + kx)) * 8;
            float4 a = ld4(ip), c4 = ld4(ip + 4);
            float in8[8] = {a.x, a.y, a.z, a.w, c4.x, c4.y, c4.z, c4.w};
            const float* wp = w + tap * 8 * 16;
            #pragma unroll
            for (int ci = 0; ci < 8; ++ci)
                #pragma unroll
                for (int co = 0; co < 16; ++co)
                    acc[co] = fmaf(in8[ci], wp[ci * 16 + co], acc[co]);
        }
        #pragma unroll
        for (int co = 0; co < 16; ++co)
            best[co] = fmaxf(best[co], fmaxf(acc[co], 0.f));
    }
    float* op = y2 + (size_t)t * 16;
    #pragma unroll
    for (int c = 0; c < 16; ++c) {
        float s = g[c] / sqrtf(vr[c] + 1.0e-3f);
        op[c] = fmaf(s, best[c], bb[c] - mn[c] * s);
    }
}

// ---------------- tiled conv core: 16x16 outputs/block, 18x18xCIN LDS tile ----------------
template<int CIN, int CIN_P, int SIN>
__device__ __forceinline__ void conv_tile_compute(
    const float* __restrict__ in_b, const float* __restrict__ w,
    const float* __restrict__ bias, float* lds,
    int ty, int tx, int lty, int ltx, int tid, float acc[32])
{
    const int CINq = CIN / 4;
    const int TOT = 18 * 18 * CINq;       // float4 units to stage
    int y0 = ty * 16, x0 = tx * 16;
    for (int i = tid; i < TOT; i += 256) {
        int pix = i / CINq, q = i - pix * CINq;
        int r = pix / 18, c = pix - r * 18;
        int gy = min(y0 + r, SIN - 1), gx = min(x0 + c, SIN - 1);  // clamp: only feeds masked lanes
        float4 v = ld4(in_b + ((size_t)gy * SIN + gx) * CIN + q * 4);
        st4s(lds + (r * 18 + c) * CIN_P + q * 4, v);
    }
    __syncthreads();
    #pragma unroll
    for (int c = 0; c < 32; ++c) acc[c] = bias[c];
    const float* wt = w;
    #pragma unroll 1
    for (int tap = 0; tap < 9; ++tap) {
        int ky = tap / 3, kx = tap - ky * 3;
        const float* lp = lds + ((lty + ky) * 18 + (ltx + kx)) * CIN_P;
        float v[CIN];
        #pragma unroll
        for (int q = 0; q < CINq; ++q) {
            float4 t4 = *reinterpret_cast<const float4*>(lp + q * 4);
            v[q * 4 + 0] = t4.x; v[q * 4 + 1] = t4.y;
            v[q * 4 + 2] = t4.z; v[q * 4 + 3] = t4.w;
        }
        #pragma unroll
        for (int ci = 0; ci < CIN; ++ci)
            #pragma unroll
            for (int co = 0; co < 32; ++co)
                acc[co] = fmaf(v[ci], wt[ci * 32 + co], acc[co]);
        wt += CIN * 32;
    }
}

// ---------------- conv3 (3x3,16->32) + relu + bn3, tiled ----------------
__global__ void __launch_bounds__(256) conv3t_k(
    const float* __restrict__ y2, float* __restrict__ y3,
    const float* __restrict__ w, const float* __restrict__ bias,
    const float* __restrict__ g, const float* __restrict__ bb,
    const float* __restrict__ mn, const float* __restrict__ vr)
{
    const int SIN = 126, SOUT = 124;      // 8x8 tiles
    __shared__ float lds[18 * 18 * 20];   // 25.9 KB
    int blk = blockIdx.x;
    int b = blk >> 6; int tt = blk & 63; int ty = tt >> 3, tx = tt & 7;
    int tid = threadIdx.x, lty = tid >> 4, ltx = tid & 15;
    float acc[32];
    conv_tile_compute<16, 20, 126>(y2 + (size_t)b * SIN * SIN * 16, w, bias,
                                   lds, ty, tx, lty, ltx, tid, acc);
    int oy = ty * 16 + lty, ox = tx * 16 + ltx;
    if (oy < SOUT && ox < SOUT) {
        float* op = y3 + ((size_t)b * SOUT * SOUT + (size_t)oy * SOUT + ox) * 32;
        #pragma unroll
        for (int c = 0; c < 32; ++c) {
            float z = fmaxf(acc[c], 0.f);
            float s = g[c] / sqrtf(vr[c] + 1.0e-3f);
            op[c] = fmaf(s, z, bb[c] - mn[c] * s);
        }
    }
}

// ---------------- conv4 (3x3,32->32) + relu + global max per (b,c), tiled ----------------
__global__ void __launch_bounds__(256) conv4t_k(
    const float* __restrict__ y3, float* __restrict__ maxbuf,
    const float* __restrict__ w, const float* __restrict__ bias)
{
    const int SIN = 124, SOUT = 122;      // 8x8 tiles
    __shared__ float lds[18 * 18 * 36];   // 46.7 KB
    __shared__ float red[4 * 32];
    int blk = blockIdx.x;
    int b = blk >> 6; int tt = blk & 63; int ty = tt >> 3, tx = tt & 7;
    int tid = threadIdx.x, lty = tid >> 4, ltx = tid & 15;
    float acc[32];
    conv_tile_compute<32, 36, 124>(y3 + (size_t)b * SIN * SIN * 32, w, bias,
                                   lds, ty, tx, lty, ltx, tid, acc);
    int oy = ty * 16 + lty, ox = tx * 16 + ltx;
    bool valid = (oy < SOUT) && (ox < SOUT);
    #pragma unroll
    for (int c = 0; c < 32; ++c)
        acc[c] = valid ? fmaxf(acc[c], 0.f) : 0.f;   // relu >= 0, masked lanes neutral
    int lane = tid & 63, wid = tid >> 6;
    #pragma unroll 1
    for (int c = 0; c < 32; ++c) {
        float v = acc[c];
        #pragma unroll
        for (int off = 32; off >= 1; off >>= 1)
            v = fmaxf(v, __shfl_xor(v, off, 64));
        if (lane == 0) red[wid * 32 + c] = v;
    }
    __syncthreads();
    if (tid < 32) {
        int c = tid;
        float mx = fmaxf(fmaxf(red[0 * 32 + c], red[1 * 32 + c]),
                         fmaxf(red[2 * 32 + c], red[3 * 32 + c]));
        atomicMax(reinterpret_cast<int*>(maxbuf) + b * 32 + c, __float_as_int(mx));
    }
}

// ---------------- dense: h[b] = dot(max[b,:], dense_w) + dense_b ----------------
__global__ void dense_k(const float* __restrict__ maxbuf, const float* __restrict__ dw,
                        const float* __restrict__ db, float* __restrict__ hbuf,
                        float* __restrict__ out_h)
{
    int t = threadIdx.x;
    if (t < B_) {
        float acc = db[0];
        #pragma unroll
        for (int c = 0; c < 32; ++c) acc = fmaf(maxbuf[t * 32 + c], dw[c], acc);
        hbuf[t] = acc;
        out_h[t] = acc;
    }
}

// ---------------- h_maxima marker init: m0 = xc - h[b] ----------------
__global__ void minit_k(const float* __restrict__ xc, const float* __restrict__ hbuf,
                        float* __restrict__ m0)
{
    int t = blockIdx.x * blockDim.x + threadIdx.x;
    int b = t >> 14;
    if (b >= B_) return;
    float hv = hbuf[b];
    float4 a = ld4(xc + (size_t)t * 4);
    st4(m0 + (size_t)t * 4, make_float4(a.x - hv, a.y - hv, a.z - hv, a.w - hv));
}

// ---------------- fused h_maxima: 5 steps of m = min(dilate3(m), mask) per launch ----------------
// 64x32 output core per block; halo (HX=8, HY=5) -> 80x42 LDS tile.
// All tile points updated each step with edge-clamped windows: a point at
// distance d from the tile edge is valid after <=d steps; core has d>=5.
// OOB-of-image positions: marker AND mask = -inf, so min(.,-inf) keeps them
// -inf forever == exact skip-OOB dilation at image borders.
#define FS_R   5
#define FS_IW  80
#define FS_IH  42
__global__ void __launch_bounds__(256) fstep_k(
    const float* __restrict__ msrc, const float* __restrict__ mask,
    float* __restrict__ mdst)
{
    __shared__ float bufA[FS_IH * FS_IW];
    __shared__ float bufB[FS_IH * FS_IW];
    __shared__ float mk[FS_IH * FS_IW];
    const float NINF = -__builtin_inff();

    int blk = blockIdx.x;
    int img = blk >> 5; int tt = blk & 31; int ty = tt >> 2, tx = tt & 3;
    int gy0 = ty * 32 - FS_R;     // row halo = 5
    int gx0 = tx * 64 - 8;        // col halo = 8 (keeps 16B alignment of core)
    int tid = threadIdx.x;
    const float* src_b = msrc + (size_t)img * (H_ * W_);
    const float* msk_b = mask + (size_t)img * (H_ * W_);

    // stage marker + mask tiles (OOB -> -inf)
    for (int i = tid; i < FS_IH * FS_IW; i += 256) {
        int r = i / FS_IW, c = i - r * FS_IW;
        int gy = gy0 + r, gx = gx0 + c;
        bool in = (gy >= 0) && (gy < H_) && (gx >= 0) && (gx < W_);
        int gidx = gy * W_ + gx;
        bufA[i] = in ? src_b[gidx] : NINF;
        mk[i]   = in ? msk_b[gidx] : NINF;
    }
    __syncthreads();

    float* cur = bufA;
    float* nxt = bufB;
    #pragma unroll 1
    for (int s = 0; s < FS_R; ++s) {
        // 42 rows x 20 col-quads, all updated (clamped windows at tile edges)
        for (int i = tid; i < FS_IH * (FS_IW / 4); i += 256) {
            int r = i / (FS_IW / 4), q = i - r * (FS_IW / 4);
            int c = q * 4;
            int rm = (r > 0) ? r - 1 : 0, rp = (r < FS_IH - 1) ? r + 1 : FS_IH - 1;
            float h0, h1, h2, h3;
            {   // row rm
                const float* rw = cur + rm * FS_IW;
                float4 a = *reinterpret_cast<const float4*>(rw + c);
                float L = rw[(c > 0) ? c - 1 : 0];
                float R = rw[(c + 4 < FS_IW) ? c + 4 : FS_IW - 1];
                h0 = fmaxf(fmaxf(L, a.x), a.y);
                h1 = fmaxf(fmaxf(a.x, a.y), a.z);
                h2 = fmaxf(fmaxf(a.y, a.z), a.w);
                h3 = fmaxf(fmaxf(a.z, a.w), R);
            }
            {   // row r
                const float* rw = cur + r * FS_IW;
                float4 a = *reinterpret_cast<const float4*>(rw + c);
                float L = rw[(c > 0) ? c - 1 : 0];
                float R = rw[(c + 4 < FS_IW) ? c + 4 : FS_IW - 1];
                h0 = fmaxf(h0, fmaxf(fmaxf(L, a.x), a.y));
                h1 = fmaxf(h1, fmaxf(fmaxf(a.x, a.y), a.z));
                h2 = fmaxf(h2, fmaxf(fmaxf(a.y, a.z), a.w));
                h3 = fmaxf(h3, fmaxf(fmaxf(a.z, a.w), R));
            }
            {   // row rp
                const float* rw = cur + rp * FS_IW;
                float4 a = *reinterpret_cast<const float4*>(rw + c);
                float L = rw[(c > 0) ? c - 1 : 0];
                float R = rw[(c + 4 < FS_IW) ? c + 4 : FS_IW - 1];
                h0 = fmaxf(h0, fmaxf(fmaxf(L, a.x), a.y));
                h1 = fmaxf(h1, fmaxf(fmaxf(a.x, a.y), a.z));
                h2 = fmaxf(h2, fmaxf(fmaxf(a.y, a.z), a.w));
                h3 = fmaxf(h3, fmaxf(fmaxf(a.z, a.w), R));
            }
            float4 m4 = *reinterpret_cast<const float4*>(mk + r * FS_IW + c);
            float4 o;
            o.x = fminf(h0, m4.x); o.y = fminf(h1, m4.y);
            o.z = fminf(h2, m4.z); o.w = fminf(h3, m4.w);
            *reinterpret_cast<float4*>(nxt + r * FS_IW + c) = o;
        }
        __syncthreads();
        float* tmp = cur; cur = nxt; nxt = tmp;
    }

    // write back 64x32 core: LDS rows 5..36, cols 8..71 (16B-aligned)
    float* dst_b = mdst + (size_t)img * (H_ * W_);
    for (int i = tid; i < 32 * 16; i += 256) {
        int r = i >> 4, q = i & 15;
        float4 v = *reinterpret_cast<const float4*>(cur + (FS_R + r) * FS_IW + 8 + q * 4);
        *reinterpret_cast<float4*>(dst_b + (ty * 32 + r) * W_ + tx * 64 + q * 4) = v;
    }
}

extern "C" void kernel_launch(void* const* d_in, const int* in_sizes, int n_in,
                              void* d_out, int out_size, void* d_ws, size_t ws_size,
                              hipStream_t stream) {
    const float* x    = (const float*)d_in[0];
    const float* ko   = (const float*)d_in[1];
    const float* kc   = (const float*)d_in[2];
    const float* c1w  = (const float*)d_in[3];
    const float* c1b  = (const float*)d_in[4];
    const float* c2w  = (const float*)d_in[5];
    const float* c2b  = (const float*)d_in[6];
    const float* c3w  = (const float*)d_in[7];
    const float* c3b  = (const float*)d_in[8];
    const float* c4w  = (const float*)d_in[9];
    const float* c4b  = (const float*)d_in[10];
    const float* bn1g = (const float*)d_in[11];
    const float* bn1b = (const float*)d_in[12];
    const float* bn1m = (const float*)d_in[13];
    const float* bn1v = (const float*)d_in[14];
    const float* bn2g = (const float*)d_in[15];
    const float* bn2b = (const float*)d_in[16];
    const float* bn2m = (const float*)d_in[17];
    const float* bn2v = (const float*)d_in[18];
    const float* bn3g = (const float*)d_in[19];
    const float* bn3b = (const float*)d_in[20];
    const float* bn3m = (const float*)d_in[21];
    const float* bn3v = (const float*)d_in[22];
    const float* dw   = (const float*)d_in[23];
    const float* db   = (const float*)d_in[24];
    float* out = (float*)d_out;
    float* ws  = (float*)d_ws;

    // workspace layout (floats): xc [0,2M) | A [2M,18.6M) | Bbuf | maxbuf | hbuf
    float* xc     = ws;
    float* A      = ws + 2097152;
    float* Bbuf   = ws + 18613248;
    float* maxbuf = ws + 26741760;
    float* hbuf   = ws + 26742784;
    float* t0 = A;
    float* t1 = A + 2097152;

    const int NQ_BLOCKS = (B_ * H_ * W_ / 4) / 256;  // 2048

    // morphological open then close
    morph_k<0><<<NQ_BLOCKS, 256, 0, stream>>>(x,  t0, ko);   // erosion
    morph_k<1><<<NQ_BLOCKS, 256, 0, stream>>>(t0, t1, ko);   // dilation -> xo
    morph_k<1><<<NQ_BLOCKS, 256, 0, stream>>>(t1, t0, kc);   // dilation
    morph_k<0><<<NQ_BLOCKS, 256, 0, stream>>>(t0, xc, kc);   // erosion  -> xc

    conv1_k<<<(B_ * 254 * 254 + 255) / 256, 256, 0, stream>>>(xc, A, c1w, c1b,
                                                              bn1g, bn1b, bn1m, bn1v);
    conv2_k<<<(B_ * 126 * 126 + 255) / 256, 256, 0, stream>>>(A, Bbuf, c2w, c2b,
                                                              bn2g, bn2b, bn2m, bn2v);
    conv3t_k<<<B_ * 64, 256, 0, stream>>>(Bbuf, A, c3w, c3b, bn3g, bn3b, bn3m, bn3v);
    hipMemsetAsync(maxbuf, 0, 32 * 32 * sizeof(float), stream);
    conv4t_k<<<B_ * 64, 256, 0, stream>>>(A, maxbuf, c4w, c4b);
    dense_k<<<1, 64, 0, stream>>>(maxbuf, dw, db, hbuf, out + B_ * H_ * W_);

    // h-maxima: marker = xc - h; 10 launches x 5 fused steps; last writes d_out
    minit_k<<<NQ_BLOCKS, 256, 0, stream>>>(xc, hbuf, t0);
    for (int j = 0; j < 10; ++j) {
        const float* src = (j & 1) ? t1 : t0;
        float* dst = (j == 9) ? out : ((j & 1) ? t0 : t1);
        fstep_k<<<B_ * 32, 256, 0, stream>>>(src, xc, dst);
    }
}

// Round 6
// 573.624 us; speedup vs baseline: 2.0893x; 1.1750x over previous
//
#include <hip/hip_runtime.h>

// Pipeline: morph open/close -> conv1+bn1 -> conv2+pool+bn2 (tiled) -> conv3+bn3
//           -> conv4+globalmax -> dense -> h_maxima (10x 5-step fused dilate+min)
// All fp32. conv2/3/4 LDS-tiled; conv4 CIN-chunked (2x16) so LDS=25.9KB -> 6 blocks/CU.

#define B_ 32
#define H_ 256
#define W_ 256

__device__ __forceinline__ float4 ld4(const float* p){ return *reinterpret_cast<const float4*>(p); }
__device__ __forceinline__ void st4(float* p, float4 v){ *reinterpret_cast<float4*>(p) = v; }
__device__ __forceinline__ void st4s(float* p, float4 v){ *reinterpret_cast<float4*>(p) = v; }

// ---------------- morphology: 3x3 dilation (max, +k) / erosion (min, -k_flipped) ----------------
template<int IS_MAX>
__global__ void morph_k(const float* __restrict__ in, float* __restrict__ out,
                        const float* __restrict__ k9)
{
    int t = blockIdx.x * blockDim.x + threadIdx.x;     // quad index
    int xq = t & 63; int y = (t >> 6) & 255; int b = t >> 14;
    if (b >= B_) return;
    const float INF = __builtin_inff();
    const float* img = in + (size_t)b * (H_ * W_);
    int x0 = xq * 4;
    float res[4];
    #pragma unroll
    for (int j = 0; j < 4; ++j) res[j] = IS_MAX ? -INF : INF;
    #pragma unroll
    for (int di = -1; di <= 1; ++di) {
        int yy = y + di;
        if (yy < 0 || yy >= H_) continue;
        const float* row = img + yy * W_;
        float w[6];
        w[0] = (x0 > 0) ? row[x0 - 1] : (IS_MAX ? -INF : INF);
        float4 m = ld4(row + x0);
        w[1] = m.x; w[2] = m.y; w[3] = m.z; w[4] = m.w;
        w[5] = (x0 + 4 < W_) ? row[x0 + 4] : (IS_MAX ? -INF : INF);
        #pragma unroll
        for (int dj = -1; dj <= 1; ++dj) {
            float kv = IS_MAX ? k9[(di + 1) * 3 + (dj + 1)]
                              : k9[(1 - di) * 3 + (1 - dj)];
            #pragma unroll
            for (int j = 0; j < 4; ++j) {
                float v = IS_MAX ? (w[j + 1 + dj] + kv) : (w[j + 1 + dj] - kv);
                res[j] = IS_MAX ? fmaxf(res[j], v) : fminf(res[j], v);
            }
        }
    }
    st4(out + (size_t)b * (H_ * W_) + y * W_ + x0,
        make_float4(res[0], res[1], res[2], res[3]));
}

// ---------------- conv1 (3x3,1->8) + relu + bn1 ----------------
__global__ void conv1_k(const float* __restrict__ xc, float* __restrict__ y1,
                        const float* __restrict__ w, const float* __restrict__ bias,
                        const float* __restrict__ g, const float* __restrict__ bb,
                        const float* __restrict__ mn, const float* __restrict__ vr)
{
    const int S = 254;
    int t = blockIdx.x * blockDim.x + threadIdx.x;
    int total = B_ * S * S;
    if (t >= total) return;
    int x = t % S; int y = (t / S) % S; int b = t / (S * S);
    const float* img = xc + (size_t)b * H_ * W_;
    float acc[8];
    #pragma unroll
    for (int c = 0; c < 8; ++c) acc[c] = bias[c];
    #pragma unroll
    for (int ky = 0; ky < 3; ++ky) {
        #pragma unroll
        for (int kx = 0; kx < 3; ++kx) {
            float iv = img[(y + ky) * W_ + (x + kx)];
            const float* wp = w + (ky * 3 + kx) * 8;
            #pragma unroll
            for (int c = 0; c < 8; ++c) acc[c] = fmaf(iv, wp[c], acc[c]);
        }
    }
    float* op = y1 + (size_t)t * 8;
    #pragma unroll
    for (int c = 0; c < 8; ++c) {
        float z = fmaxf(acc[c], 0.f);
        float s = g[c] / sqrtf(vr[c] + 1.0e-3f);
        op[c] = fmaf(s, z, bb[c] - mn[c] * s);
    }
}

// ---------------- conv2 (3x3,8->16) + relu + maxpool2 + bn2, tiled ----------------
// Block: 16x16 pooled outputs (= 32x32 conv outputs), 34x34x8 y1 tile in LDS (SoA).
#define C2_PITCH (34 * 34 + 2)
__global__ void __launch_bounds__(256) conv2t_k(
    const float* __restrict__ y1, float* __restrict__ y2,
    const float* __restrict__ w, const float* __restrict__ bias,
    const float* __restrict__ g, const float* __restrict__ bb,
    const float* __restrict__ mn, const float* __restrict__ vr)
{
    const int SIN = 254, POUT = 126;
    __shared__ float lds[8 * C2_PITCH];    // 37.1 KB
    int blk = blockIdx.x;
    int b = blk >> 6; int tt = blk & 63; int ty = tt >> 3, tx = tt & 7;
    int cy0 = ty * 32, cx0 = tx * 32;      // conv-output/tile-input origin
    int tid = threadIdx.x;
    const float* in_b = y1 + (size_t)b * SIN * SIN * 8;

    for (int i = tid; i < 34 * 34; i += 256) {
        int r = i / 34, c = i - r * 34;
        int gy = min(cy0 + r, SIN - 1), gx = min(cx0 + c, SIN - 1);  // clamp feeds masked lanes only
        const float* p = in_b + ((size_t)gy * SIN + gx) * 8;
        float4 a = ld4(p), d = ld4(p + 4);
        lds[0 * C2_PITCH + i] = a.x; lds[1 * C2_PITCH + i] = a.y;
        lds[2 * C2_PITCH + i] = a.z; lds[3 * C2_PITCH + i] = a.w;
        lds[4 * C2_PITCH + i] = d.x; lds[5 * C2_PITCH + i] = d.y;
        lds[6 * C2_PITCH + i] = d.z; lds[7 * C2_PITCH + i] = d.w;
    }
    __syncthreads();

    int lty = tid >> 4, ltx = tid & 15;
    float acc[4][16];
    #pragma unroll
    for (int pos = 0; pos < 4; ++pos)
        #pragma unroll
        for (int c = 0; c < 16; ++c) acc[pos][c] = bias[c];

    #pragma unroll 1
    for (int tap = 0; tap < 9; ++tap) {
        int ky = tap / 3, kx = tap - ky * 3;
        const float* wp = w + tap * 8 * 16;
        #pragma unroll
        for (int pos = 0; pos < 4; ++pos) {
            int pix = (2 * lty + (pos >> 1) + ky) * 34 + (2 * ltx + (pos & 1) + kx);
            float in8[8];
            #pragma unroll
            for (int ci = 0; ci < 8; ++ci) in8[ci] = lds[ci * C2_PITCH + pix];
            #pragma unroll
            for (int ci = 0; ci < 8; ++ci)
                #pragma unroll
                for (int co = 0; co < 16; ++co)
                    acc[pos][co] = fmaf(in8[ci], wp[ci * 16 + co], acc[pos][co]);
        }
    }

    int py = ty * 16 + lty, px = tx * 16 + ltx;
    if (py < POUT && px < POUT) {
        float* op = y2 + ((size_t)b * POUT * POUT + (size_t)py * POUT + px) * 16;
        #pragma unroll
        for (int co = 0; co < 16; ++co) {
            float bst = fmaxf(fmaxf(fmaxf(acc[0][co], 0.f), fmaxf(acc[1][co], 0.f)),
                              fmaxf(fmaxf(acc[2][co], 0.f), fmaxf(acc[3][co], 0.f)));
            float s = g[co] / sqrtf(vr[co] + 1.0e-3f);
            op[co] = fmaf(s, bst, bb[co] - mn[co] * s);
        }
    }
}

// ---------------- chunked tiled conv core: 16x16 outputs/block, 18x18xCHUNK LDS ----------------
// Stages CIN in NCH chunks; acc[32] persists across chunks (bit-identical to one pass).
template<int CIN, int NCH, int CHP, int SIN>
__device__ __forceinline__ void conv_tile_chunked(
    const float* __restrict__ in_b, const float* __restrict__ w,
    const float* __restrict__ bias, float* lds,
    int y0, int x0, int lty, int ltx, int tid, float acc[32])
{
    const int CHUNK = CIN / NCH, CHQ = CHUNK / 4;
    #pragma unroll
    for (int c = 0; c < 32; ++c) acc[c] = bias[c];
    #pragma unroll 1
    for (int ch = 0; ch < NCH; ++ch) {
        int ci0 = ch * CHUNK;
        if (ch) __syncthreads();           // all readers done before restage
        const int TOT = 18 * 18 * CHQ;
        for (int i = tid; i < TOT; i += 256) {
            int pix = i / CHQ, q = i - pix * CHQ;
            int r = pix / 18, c = pix - r * 18;
            int gy = min(y0 + r, SIN - 1), gx = min(x0 + c, SIN - 1);
            float4 v = ld4(in_b + ((size_t)gy * SIN + gx) * CIN + ci0 + q * 4);
            st4s(lds + (r * 18 + c) * CHP + q * 4, v);
        }
        __syncthreads();
        const float* wb = w + ci0 * 32;
        #pragma unroll 1
        for (int tap = 0; tap < 9; ++tap) {
            int ky = tap / 3, kx = tap - ky * 3;
            const float* lp = lds + ((lty + ky) * 18 + (ltx + kx)) * CHP;
            float v[CHUNK];
            #pragma unroll
            for (int q = 0; q < CHQ; ++q) {
                float4 t4 = *reinterpret_cast<const float4*>(lp + q * 4);
                v[q * 4 + 0] = t4.x; v[q * 4 + 1] = t4.y;
                v[q * 4 + 2] = t4.z; v[q * 4 + 3] = t4.w;
            }
            const float* wt = wb + tap * CIN * 32;
            #pragma unroll
            for (int ci = 0; ci < CHUNK; ++ci)
                #pragma unroll
                for (int co = 0; co < 32; ++co)
                    acc[co] = fmaf(v[ci], wt[ci * 32 + co], acc[co]);
        }
    }
}

// ---------------- conv3 (3x3,16->32) + relu + bn3, tiled ----------------
__global__ void __launch_bounds__(256) conv3t_k(
    const float* __restrict__ y2, float* __restrict__ y3,
    const float* __restrict__ w, const float* __restrict__ bias,
    const float* __restrict__ g, const float* __restrict__ bb,
    const float* __restrict__ mn, const float* __restrict__ vr)
{
    const int SIN = 126, SOUT = 124;      // 8x8 tiles
    __shared__ float lds[18 * 18 * 20];   // 25.9 KB
    int blk = blockIdx.x;
    int b = blk >> 6; int tt = blk & 63; int ty = tt >> 3, tx = tt & 7;
    int tid = threadIdx.x, lty = tid >> 4, ltx = tid & 15;
    float acc[32];
    conv_tile_chunked<16, 1, 20, 126>(y2 + (size_t)b * SIN * SIN * 16, w, bias,
                                      lds, ty * 16, tx * 16, lty, ltx, tid, acc);
    int oy = ty * 16 + lty, ox = tx * 16 + ltx;
    if (oy < SOUT && ox < SOUT) {
        float* op = y3 + ((size_t)b * SOUT * SOUT + (size_t)oy * SOUT + ox) * 32;
        #pragma unroll
        for (int c = 0; c < 32; ++c) {
            float z = fmaxf(acc[c], 0.f);
            float s = g[c] / sqrtf(vr[c] + 1.0e-3f);
            op[c] = fmaf(s, z, bb[c] - mn[c] * s);
        }
    }
}

// ---------------- conv4 (3x3,32->32) + relu + global max per (b,c), tiled+chunked ----------------
__global__ void __launch_bounds__(256) conv4t_k(
    const float* __restrict__ y3, float* __restrict__ maxbuf,
    const float* __restrict__ w, const float* __restrict__ bias)
{
    const int SIN = 124, SOUT = 122;      // 8x8 tiles
    __shared__ float lds[18 * 18 * 20];   // 25.9 KB (chunk = 16 ch)
    __shared__ float red[4 * 32];
    int blk = blockIdx.x;
    int b = blk >> 6; int tt = blk & 63; int ty = tt >> 3, tx = tt & 7;
    int tid = threadIdx.x, lty = tid >> 4, ltx = tid & 15;
    float acc[32];
    conv_tile_chunked<32, 2, 20, 124>(y3 + (size_t)b * SIN * SIN * 32, w, bias,
                                      lds, ty * 16, tx * 16, lty, ltx, tid, acc);
    int oy = ty * 16 + lty, ox = tx * 16 + ltx;
    bool valid = (oy < SOUT) && (ox < SOUT);
    #pragma unroll
    for (int c = 0; c < 32; ++c)
        acc[c] = valid ? fmaxf(acc[c], 0.f) : 0.f;   // relu >= 0, masked lanes neutral
    int lane = tid & 63, wid = tid >> 6;
    #pragma unroll 1
    for (int c = 0; c < 32; ++c) {
        float v = acc[c];
        #pragma unroll
        for (int off = 32; off >= 1; off >>= 1)
            v = fmaxf(v, __shfl_xor(v, off, 64));
        if (lane == 0) red[wid * 32 + c] = v;
    }
    __syncthreads();
    if (tid < 32) {
        int c = tid;
        float mx = fmaxf(fmaxf(red[0 * 32 + c], red[1 * 32 + c]),
                         fmaxf(red[2 * 32 + c], red[3 * 32 + c]));
        atomicMax(reinterpret_cast<int*>(maxbuf) + b * 32 + c, __float_as_int(mx));
    }
}

// ---------------- dense: h[b] = dot(max[b,:], dense_w) + dense_b ----------------
__global__ void dense_k(const float* __restrict__ maxbuf, const float* __restrict__ dw,
                        const float* __restrict__ db, float* __restrict__ hbuf,
                        float* __restrict__ out_h)
{
    int t = threadIdx.x;
    if (t < B_) {
        float acc = db[0];
        #pragma unroll
        for (int c = 0; c < 32; ++c) acc = fmaf(maxbuf[t * 32 + c], dw[c], acc);
        hbuf[t] = acc;
        out_h[t] = acc;
    }
}

// ---------------- h_maxima marker init: m0 = xc - h[b] ----------------
__global__ void minit_k(const float* __restrict__ xc, const float* __restrict__ hbuf,
                        float* __restrict__ m0)
{
    int t = blockIdx.x * blockDim.x + threadIdx.x;
    int b = t >> 14;
    if (b >= B_) return;
    float hv = hbuf[b];
    float4 a = ld4(xc + (size_t)t * 4);
    st4(m0 + (size_t)t * 4, make_float4(a.x - hv, a.y - hv, a.z - hv, a.w - hv));
}

// ---------------- fused h_maxima: 5 steps of m = min(dilate3(m), mask) per launch ----------------
#define FS_R   5
#define FS_IW  80
#define FS_IH  42
__global__ void __launch_bounds__(256) fstep_k(
    const float* __restrict__ msrc, const float* __restrict__ mask,
    float* __restrict__ mdst)
{
    __shared__ float bufA[FS_IH * FS_IW];
    __shared__ float bufB[FS_IH * FS_IW];
    __shared__ float mk[FS_IH * FS_IW];
    const float NINF = -__builtin_inff();

    int blk = blockIdx.x;
    int img = blk >> 5; int tt = blk & 31; int ty = tt >> 2, tx = tt & 3;
    int gy0 = ty * 32 - FS_R;     // row halo = 5
    int gx0 = tx * 64 - 8;        // col halo = 8 (keeps 16B alignment of core)
    int tid = threadIdx.x;
    const float* src_b = msrc + (size_t)img * (H_ * W_);
    const float* msk_b = mask + (size_t)img * (H_ * W_);

    for (int i = tid; i < FS_IH * FS_IW; i += 256) {
        int r = i / FS_IW, c = i - r * FS_IW;
        int gy = gy0 + r, gx = gx0 + c;
        bool in = (gy >= 0) && (gy < H_) && (gx >= 0) && (gx < W_);
        int gidx = gy * W_ + gx;
        bufA[i] = in ? src_b[gidx] : NINF;
        mk[i]   = in ? msk_b[gidx] : NINF;
    }
    __syncthreads();

    float* cur = bufA;
    float* nxt = bufB;
    #pragma unroll 1
    for (int s = 0; s < FS_R; ++s) {
        for (int i = tid; i < FS_IH * (FS_IW / 4); i += 256) {
            int r = i / (FS_IW / 4), q = i - r * (FS_IW / 4);
            int c = q * 4;
            int rm = (r > 0) ? r - 1 : 0, rp = (r < FS_IH - 1) ? r + 1 : FS_IH - 1;
            float h0, h1, h2, h3;
            {
                const float* rw = cur + rm * FS_IW;
                float4 a = *reinterpret_cast<const float4*>(rw + c);
                float L = rw[(c > 0) ? c - 1 : 0];
                float R = rw[(c + 4 < FS_IW) ? c + 4 : FS_IW - 1];
                h0 = fmaxf(fmaxf(L, a.x), a.y);
                h1 = fmaxf(fmaxf(a.x, a.y), a.z);
                h2 = fmaxf(fmaxf(a.y, a.z), a.w);
                h3 = fmaxf(fmaxf(a.z, a.w), R);
            }
            {
                const float* rw = cur + r * FS_IW;
                float4 a = *reinterpret_cast<const float4*>(rw + c);
                float L = rw[(c > 0) ? c - 1 : 0];
                float R = rw[(c + 4 < FS_IW) ? c + 4 : FS_IW - 1];
                h0 = fmaxf(h0, fmaxf(fmaxf(L, a.x), a.y));
                h1 = fmaxf(h1, fmaxf(fmaxf(a.x, a.y), a.z));
                h2 = fmaxf(h2, fmaxf(fmaxf(a.y, a.z), a.w));
                h3 = fmaxf(h3, fmaxf(fmaxf(a.z, a.w), R));
            }
            {
                const float* rw = cur + rp * FS_IW;
                float4 a = *reinterpret_cast<const float4*>(rw + c);
                float L = rw[(c > 0) ? c - 1 : 0];
                float R = rw[(c + 4 < FS_IW) ? c + 4 : FS_IW - 1];
                h0 = fmaxf(h0, fmaxf(fmaxf(L, a.x), a.y));
                h1 = fmaxf(h1, fmaxf(fmaxf(a.x, a.y), a.z));
                h2 = fmaxf(h2, fmaxf(fmaxf(a.y, a.z), a.w));
                h3 = fmaxf(h3, fmaxf(fmaxf(a.z, a.w), R));
            }
            float4 m4 = *reinterpret_cast<const float4*>(mk + r * FS_IW + c);
            float4 o;
            o.x = fminf(h0, m4.x); o.y = fminf(h1, m4.y);
            o.z = fminf(h2, m4.z); o.w = fminf(h3, m4.w);
            *reinterpret_cast<float4*>(nxt + r * FS_IW + c) = o;
        }
        __syncthreads();
        float* tmp = cur; cur = nxt; nxt = tmp;
    }

    float* dst_b = mdst + (size_t)img * (H_ * W_);
    for (int i = tid; i < 32 * 16; i += 256) {
        int r = i >> 4, q = i & 15;
        float4 v = *reinterpret_cast<const float4*>(cur + (FS_R + r) * FS_IW + 8 + q * 4);
        *reinterpret_cast<float4*>(dst_b + (ty * 32 + r) * W_ + tx * 64 + q * 4) = v;
    }
}

extern "C" void kernel_launch(void* const* d_in, const int* in_sizes, int n_in,
                              void* d_out, int out_size, void* d_ws, size_t ws_size,
                              hipStream_t stream) {
    const float* x    = (const float*)d_in[0];
    const float* ko   = (const float*)d_in[1];
    const float* kc   = (const float*)d_in[2];
    const float* c1w  = (const float*)d_in[3];
    const float* c1b  = (const float*)d_in[4];
    const float* c2w  = (const float*)d_in[5];
    const float* c2b  = (const float*)d_in[6];
    const float* c3w  = (const float*)d_in[7];
    const float* c3b  = (const float*)d_in[8];
    const float* c4w  = (const float*)d_in[9];
    const float* c4b  = (const float*)d_in[10];
    const float* bn1g = (const float*)d_in[11];
    const float* bn1b = (const float*)d_in[12];
    const float* bn1m = (const float*)d_in[13];
    const float* bn1v = (const float*)d_in[14];
    const float* bn2g = (const float*)d_in[15];
    const float* bn2b = (const float*)d_in[16];
    const float* bn2m = (const float*)d_in[17];
    const float* bn2v = (const float*)d_in[18];
    const float* bn3g = (const float*)d_in[19];
    const float* bn3b = (const float*)d_in[20];
    const float* bn3m = (const float*)d_in[21];
    const float* bn3v = (const float*)d_in[22];
    const float* dw   = (const float*)d_in[23];
    const float* db   = (const float*)d_in[24];
    float* out = (float*)d_out;
    float* ws  = (float*)d_ws;

    // workspace layout (floats): xc [0,2M) | A [2M,18.6M) | Bbuf | maxbuf | hbuf
    float* xc     = ws;
    float* A      = ws + 2097152;
    float* Bbuf   = ws + 18613248;
    float* maxbuf = ws + 26741760;
    float* hbuf   = ws + 26742784;
    float* t0 = A;
    float* t1 = A + 2097152;

    const int NQ_BLOCKS = (B_ * H_ * W_ / 4) / 256;  // 2048

    // morphological open then close
    morph_k<0><<<NQ_BLOCKS, 256, 0, stream>>>(x,  t0, ko);   // erosion
    morph_k<1><<<NQ_BLOCKS, 256, 0, stream>>>(t0, t1, ko);   // dilation -> xo
    morph_k<1><<<NQ_BLOCKS, 256, 0, stream>>>(t1, t0, kc);   // dilation
    morph_k<0><<<NQ_BLOCKS, 256, 0, stream>>>(t0, xc, kc);   // erosion  -> xc

    conv1_k<<<(B_ * 254 * 254 + 255) / 256, 256, 0, stream>>>(xc, A, c1w, c1b,
                                                              bn1g, bn1b, bn1m, bn1v);
    conv2t_k<<<B_ * 64, 256, 0, stream>>>(A, Bbuf, c2w, c2b, bn2g, bn2b, bn2m, bn2v);
    conv3t_k<<<B_ * 64, 256, 0, stream>>>(Bbuf, A, c3w, c3b, bn3g, bn3b, bn3m, bn3v);
    hipMemsetAsync(maxbuf, 0, 32 * 32 * sizeof(float), stream);
    conv4t_k<<<B_ * 64, 256, 0, stream>>>(A, maxbuf, c4w, c4b);
    dense_k<<<1, 64, 0, stream>>>(maxbuf, dw, db, hbuf, out + B_ * H_ * W_);

    // h-maxima: marker = xc - h; 10 launches x 5 fused steps; last writes d_out
    minit_k<<<NQ_BLOCKS, 256, 0, stream>>>(xc, hbuf, t0);
    for (int j = 0; j < 10; ++j) {
        const float* src = (j & 1) ? t1 : t0;
        float* dst = (j == 9) ? out : ((j & 1) ? t0 : t1);
        fstep_k<<<B_ * 32, 256, 0, stream>>>(src, xc, dst);
    }
}